// Round 6
// baseline (1226.640 us; speedup 1.0000x reference)
//
#include <hip/hip_runtime.h>

#define N_NODES 100000
#define N_EDGES 1200000
#define DIM 64
#define SCAN_BLOCK 256
#define NB ((N_NODES + SCAN_BLOCK - 1) / SCAN_BLOCK)  // 391

__device__ __forceinline__ float lane_bcast(float v, int k) {
  return __int_as_float(__builtin_amdgcn_readlane(__float_as_int(v), k));
}

// butterfly-sum a float4 across the four 16-lane groups (xor 16, then 32)
__device__ __forceinline__ float4 qsum(float4 v) {
  v.x += __shfl_xor(v.x, 16); v.y += __shfl_xor(v.y, 16);
  v.z += __shfl_xor(v.z, 16); v.w += __shfl_xor(v.w, 16);
  v.x += __shfl_xor(v.x, 32); v.y += __shfl_xor(v.y, 32);
  v.z += __shfl_xor(v.z, 32); v.w += __shfl_xor(v.w, 32);
  return v;
}

// ---- CSR build ------------------------------------------------------------

__global__ __launch_bounds__(256) void hist_deg(
    const int* __restrict__ dst, int* __restrict__ deg, int nEdges) {
  int e = blockIdx.x * blockDim.x + threadIdx.x;
  if (e < nEdges) atomicAdd(&deg[dst[e]], 1);
}

__global__ __launch_bounds__(SCAN_BLOCK) void block_sums(
    const int* __restrict__ deg, int* __restrict__ bsums, int n) {
  __shared__ int s[SCAN_BLOCK];
  int i = blockIdx.x * SCAN_BLOCK + threadIdx.x;
  s[threadIdx.x] = (i < n) ? deg[i] : 0;
  __syncthreads();
  for (int off = SCAN_BLOCK / 2; off > 0; off >>= 1) {
    if (threadIdx.x < off) s[threadIdx.x] += s[threadIdx.x + off];
    __syncthreads();
  }
  if (threadIdx.x == 0) bsums[blockIdx.x] = s[0];
}

__global__ __launch_bounds__(512) void scan_bsums(int* __restrict__ bsums, int nb) {
  __shared__ int s[512];
  int tid = threadIdx.x;
  s[tid] = (tid < nb) ? bsums[tid] : 0;
  __syncthreads();
  for (int off = 1; off < 512; off <<= 1) {
    int v = (tid >= off) ? s[tid - off] : 0;
    __syncthreads();
    s[tid] += v;
    __syncthreads();
  }
  if (tid < nb) bsums[tid] = (tid == 0) ? 0 : s[tid - 1];  // exclusive base
}

__global__ __launch_bounds__(SCAN_BLOCK) void scan_final(
    const int* __restrict__ deg, const int* __restrict__ bbase,
    int* __restrict__ offs, int* __restrict__ cursor, int n) {
  __shared__ int s[SCAN_BLOCK];
  int i = blockIdx.x * SCAN_BLOCK + threadIdx.x;
  int v = (i < n) ? deg[i] : 0;
  s[threadIdx.x] = v;
  __syncthreads();
  for (int off = 1; off < SCAN_BLOCK; off <<= 1) {
    int t = (threadIdx.x >= off) ? s[threadIdx.x - off] : 0;
    __syncthreads();
    s[threadIdx.x] += t;
    __syncthreads();
  }
  int base = bbase[blockIdx.x];
  if (i < n) {
    int excl = base + s[threadIdx.x] - v;
    offs[i] = excl;
    cursor[i] = excl;
  }
  if (i == n - 1) offs[n] = base + s[threadIdx.x];
}

__global__ __launch_bounds__(256) void fill_csr(
    const int* __restrict__ src, const int* __restrict__ dst,
    int* __restrict__ cursor, int* __restrict__ csr_src, int nEdges) {
  int e = blockIdx.x * blockDim.x + threadIdx.x;
  if (e < nEdges) {
    int p = atomicAdd(&cursor[dst[e]], 1);
    csr_src[p] = src[e];
  }
}

// ---- Fused SAGE layer v4 --------------------------------------------------
// Gather phase: wave = (q,r) lanes; one instruction gathers 4 edges x 16B/lane
// (1 KB/wave-inst, 4x fewer insts + addr VALU than scalar; 2 independent
// chains across the node pair). Cross-q reduce via shfl_xor(16,32).
// Matvec phase: lane j owns dim j; weights in LDS (sW[k*64+j]: 2 lanes/bank,
// free); mean/self broadcast via readlane from float4 groups.
// 512-thr blocks, launch_bounds(512,6): 3 blocks/CU x 8 waves = 24 waves/CU
// (round-5 was 26% occupancy; latency-bound).
__global__ __launch_bounds__(512, 6) void sage_fused(
    const float* __restrict__ xin, const int* __restrict__ offs,
    const int* __restrict__ csr_src, const float* __restrict__ Wn,
    const float* __restrict__ Ws, const float* __restrict__ bias,
    float* __restrict__ out, int nNodes) {
  __shared__ float sWn[DIM * DIM];
  __shared__ float sWs[DIM * DIM];
  for (int i = threadIdx.x; i < DIM * DIM / 4; i += 512) {
    reinterpret_cast<float4*>(sWn)[i] = reinterpret_cast<const float4*>(Wn)[i];
    reinterpret_cast<float4*>(sWs)[i] = reinterpret_cast<const float4*>(Ws)[i];
  }
  __syncthreads();

  const float4* xr = reinterpret_cast<const float4*>(xin);
  int lane = threadIdx.x & 63;
  int q = lane >> 4;   // edge subgroup 0..3
  int r = lane & 15;   // float4 column 0..15
  int j = lane;        // output dim in matvec phase
  int w = threadIdx.x >> 6;
  float bj = bias[j];
  int gw = blockIdx.x * 8 + w;
  int nw = gridDim.x * 8;

  for (int p = gw; 2 * p < nNodes; p += nw) {
    int n0 = 2 * p, n1 = 2 * p + 1;
    int e0a = offs[n0], e1a = offs[n0 + 1];
    int e0b = offs[n1], e1b = offs[n1 + 1];

    float4 A = {0, 0, 0, 0}, B = {0, 0, 0, 0};
    int ea = e0a, eb = e0b;
    int rem = max(e1a - e0a, e1b - e0b);
    for (; rem > 0; rem -= 4, ea += 4, eb += 4) {
      int ia = ea + q, ib = eb + q;
      if (ia < e1a) {
        float4 v = xr[(size_t)csr_src[ia] * 16 + r];
        A.x += v.x; A.y += v.y; A.z += v.z; A.w += v.w;
      }
      if (ib < e1b) {
        float4 v = xr[(size_t)csr_src[ib] * 16 + r];
        B.x += v.x; B.y += v.y; B.z += v.z; B.w += v.w;
      }
    }
    A = qsum(A);
    B = qsum(B);
    float inv0 = 1.0f / fmaxf((float)(e1a - e0a), 1.0f);
    float inv1 = 1.0f / fmaxf((float)(e1b - e0b), 1.0f);
    float m0[4] = {A.x * inv0, A.y * inv0, A.z * inv0, A.w * inv0};
    float m1[4] = {B.x * inv1, B.y * inv1, B.z * inv1, B.w * inv1};
    float4 sv0 = xr[(size_t)n0 * 16 + r];  // identical across q groups
    float4 sv1 = xr[(size_t)n1 * 16 + r];
    float s0[4] = {sv0.x, sv0.y, sv0.z, sv0.w};
    float s1[4] = {sv1.x, sv1.y, sv1.z, sv1.w};

    // dual-node matvec: lane (k>>2) holds dims [4(k>>2),4(k>>2)+4)
    float a0n = bj, a0s = 0.f, a1n = bj, a1s = 0.f;
#pragma unroll
    for (int k = 0; k < DIM; ++k) {
      float wnk = sWn[k * DIM + j];
      float wsk = sWs[k * DIM + j];
      a0n = fmaf(lane_bcast(m0[k & 3], k >> 2), wnk, a0n);
      a0s = fmaf(lane_bcast(s0[k & 3], k >> 2), wsk, a0s);
      a1n = fmaf(lane_bcast(m1[k & 3], k >> 2), wnk, a1n);
      a1s = fmaf(lane_bcast(s1[k & 3], k >> 2), wsk, a1s);
    }
    out[(size_t)n0 * DIM + j] = fmaxf(a0n + a0s, 0.0f);
    out[(size_t)n1 * DIM + j] = fmaxf(a1n + a1s, 0.0f);
  }
}

extern "C" void kernel_launch(void* const* d_in, const int* in_sizes, int n_in,
                              void* d_out, int out_size, void* d_ws, size_t ws_size,
                              hipStream_t stream) {
  const float* x   = (const float*)d_in[0];
  const int*   ei  = (const int*)d_in[1];
  const float* Wn1 = (const float*)d_in[2];
  const float* Ws1 = (const float*)d_in[3];
  const float* b1  = (const float*)d_in[4];
  const float* Wn2 = (const float*)d_in[5];
  const float* Ws2 = (const float*)d_in[6];
  const float* b2  = (const float*)d_in[7];
  const int* src = ei;
  const int* dst = ei + N_EDGES;

  // ws layout (ints): deg[N] | offs[N+1] | cursor[N] | bsums[512] | csr[E] | h1[N*64]f
  int* deg    = (int*)d_ws;
  int* offs   = deg + N_NODES;
  int* cursor = offs + N_NODES + 1;
  int* bsums  = cursor + N_NODES;
  int* csr    = bsums + 512;
  float* h1   = (float*)(csr + N_EDGES);
  float* outp = (float*)d_out;

  const int edgeBlocks = (N_EDGES + 255) / 256;
  const int fusedBlocks = 768;  // 3 blocks/CU x 8 waves = 24 waves/CU

  hipMemsetAsync(deg, 0, (size_t)N_NODES * sizeof(int), stream);
  hist_deg<<<edgeBlocks, 256, 0, stream>>>(dst, deg, N_EDGES);
  block_sums<<<NB, SCAN_BLOCK, 0, stream>>>(deg, bsums, N_NODES);
  scan_bsums<<<1, 512, 0, stream>>>(bsums, NB);
  scan_final<<<NB, SCAN_BLOCK, 0, stream>>>(deg, bsums, offs, cursor, N_NODES);
  fill_csr<<<edgeBlocks, 256, 0, stream>>>(src, dst, cursor, csr, N_EDGES);

  sage_fused<<<fusedBlocks, 512, 0, stream>>>(x, offs, csr, Wn1, Ws1, b1, h1, N_NODES);
  sage_fused<<<fusedBlocks, 512, 0, stream>>>(h1, offs, csr, Wn2, Ws2, b2, outp, N_NODES);
}

// Round 7
// 1095.256 us; speedup vs baseline: 1.1200x; 1.1200x over previous
//
#include <hip/hip_runtime.h>

#define N_NODES 100000
#define N_EDGES 1200000
#define DIM 64
#define SCAN_BLOCK 256
#define NB ((N_NODES + SCAN_BLOCK - 1) / SCAN_BLOCK)  // 391

__device__ __forceinline__ float lane_bcast(float v, int k) {
  return __int_as_float(__builtin_amdgcn_readlane(__float_as_int(v), k));
}

// butterfly-sum a float4 across the four 16-lane groups (xor 16, then 32)
__device__ __forceinline__ float4 qsum(float4 v) {
  v.x += __shfl_xor(v.x, 16); v.y += __shfl_xor(v.y, 16);
  v.z += __shfl_xor(v.z, 16); v.w += __shfl_xor(v.w, 16);
  v.x += __shfl_xor(v.x, 32); v.y += __shfl_xor(v.y, 32);
  v.z += __shfl_xor(v.z, 32); v.w += __shfl_xor(v.w, 32);
  return v;
}

// ---- CSR build ------------------------------------------------------------

__global__ __launch_bounds__(256) void hist_deg(
    const int* __restrict__ dst, int* __restrict__ deg, int nEdges) {
  int e = blockIdx.x * blockDim.x + threadIdx.x;
  if (e < nEdges) atomicAdd(&deg[dst[e]], 1);
}

__global__ __launch_bounds__(SCAN_BLOCK) void block_sums(
    const int* __restrict__ deg, int* __restrict__ bsums, int n) {
  __shared__ int s[SCAN_BLOCK];
  int i = blockIdx.x * SCAN_BLOCK + threadIdx.x;
  s[threadIdx.x] = (i < n) ? deg[i] : 0;
  __syncthreads();
  for (int off = SCAN_BLOCK / 2; off > 0; off >>= 1) {
    if (threadIdx.x < off) s[threadIdx.x] += s[threadIdx.x + off];
    __syncthreads();
  }
  if (threadIdx.x == 0) bsums[blockIdx.x] = s[0];
}

__global__ __launch_bounds__(512) void scan_bsums(int* __restrict__ bsums, int nb) {
  __shared__ int s[512];
  int tid = threadIdx.x;
  s[tid] = (tid < nb) ? bsums[tid] : 0;
  __syncthreads();
  for (int off = 1; off < 512; off <<= 1) {
    int v = (tid >= off) ? s[tid - off] : 0;
    __syncthreads();
    s[tid] += v;
    __syncthreads();
  }
  if (tid < nb) bsums[tid] = (tid == 0) ? 0 : s[tid - 1];  // exclusive base
}

__global__ __launch_bounds__(SCAN_BLOCK) void scan_final(
    const int* __restrict__ deg, const int* __restrict__ bbase,
    int* __restrict__ offs, int* __restrict__ cursor, int n) {
  __shared__ int s[SCAN_BLOCK];
  int i = blockIdx.x * SCAN_BLOCK + threadIdx.x;
  int v = (i < n) ? deg[i] : 0;
  s[threadIdx.x] = v;
  __syncthreads();
  for (int off = 1; off < SCAN_BLOCK; off <<= 1) {
    int t = (threadIdx.x >= off) ? s[threadIdx.x - off] : 0;
    __syncthreads();
    s[threadIdx.x] += t;
    __syncthreads();
  }
  int base = bbase[blockIdx.x];
  if (i < n) {
    int excl = base + s[threadIdx.x] - v;
    offs[i] = excl;
    cursor[i] = excl;
  }
  if (i == n - 1) offs[n] = base + s[threadIdx.x];
}

__global__ __launch_bounds__(256) void fill_csr(
    const int* __restrict__ src, const int* __restrict__ dst,
    int* __restrict__ cursor, int* __restrict__ csr_src, int nEdges) {
  int e = blockIdx.x * blockDim.x + threadIdx.x;
  if (e < nEdges) {
    int p = atomicAdd(&cursor[dst[e]], 1);
    csr_src[p] = src[e];
  }
}

// ---- Fused SAGE layer v5 --------------------------------------------------
// Gather: wave = (q=lane>>4, r=lane&15); one instruction gathers 4 edges x
// 16 B/lane (1 KB/wave-inst); cross-q reduce via shfl_xor(16,32). Two nodes
// interleaved = 2 independent load chains.
// Matvec: lane j owns dim j; weights in LDS (sW[k*64+j]: 2 lanes/bank, free).
// ROUND-6 LESSON: __launch_bounds__(512,6) capped VGPR at ~40 -> float4
// accumulators spilled to scratch INSIDE the gather loop (FETCH 205MB->1.47GB,
// WRITE 25->310MB, 3x regression). (256,4) leaves 128 VGPRs: no spill;
// occupancy is LDS-capped at 5 blocks/CU x 4 waves = 20 waves/CU.
__global__ __launch_bounds__(256, 4) void sage_fused(
    const float* __restrict__ xin, const int* __restrict__ offs,
    const int* __restrict__ csr_src, const float* __restrict__ Wn,
    const float* __restrict__ Ws, const float* __restrict__ bias,
    float* __restrict__ out, int nNodes) {
  __shared__ float sWn[DIM * DIM];
  __shared__ float sWs[DIM * DIM];
  for (int i = threadIdx.x; i < DIM * DIM / 4; i += 256) {
    reinterpret_cast<float4*>(sWn)[i] = reinterpret_cast<const float4*>(Wn)[i];
    reinterpret_cast<float4*>(sWs)[i] = reinterpret_cast<const float4*>(Ws)[i];
  }
  __syncthreads();

  const float4* xr = reinterpret_cast<const float4*>(xin);
  int lane = threadIdx.x & 63;
  int q = lane >> 4;   // edge subgroup 0..3
  int r = lane & 15;   // float4 column 0..15
  int j = lane;        // output dim in matvec phase
  int w = threadIdx.x >> 6;
  float bj = bias[j];
  int gw = blockIdx.x * 4 + w;
  int nw = gridDim.x * 4;

  for (int p = gw; 2 * p < nNodes; p += nw) {
    int n0 = 2 * p, n1 = 2 * p + 1;
    int e0a = offs[n0], e1a = offs[n0 + 1];
    int e0b = offs[n1], e1b = offs[n1 + 1];

    float4 A = {0, 0, 0, 0}, B = {0, 0, 0, 0};
    int ea = e0a, eb = e0b;
    int rem = max(e1a - e0a, e1b - e0b);
    for (; rem > 0; rem -= 4, ea += 4, eb += 4) {
      int ia = ea + q, ib = eb + q;
      if (ia < e1a) {
        float4 v = xr[(size_t)csr_src[ia] * 16 + r];
        A.x += v.x; A.y += v.y; A.z += v.z; A.w += v.w;
      }
      if (ib < e1b) {
        float4 v = xr[(size_t)csr_src[ib] * 16 + r];
        B.x += v.x; B.y += v.y; B.z += v.z; B.w += v.w;
      }
    }
    A = qsum(A);
    B = qsum(B);
    float inv0 = 1.0f / fmaxf((float)(e1a - e0a), 1.0f);
    float inv1 = 1.0f / fmaxf((float)(e1b - e0b), 1.0f);
    float m0[4] = {A.x * inv0, A.y * inv0, A.z * inv0, A.w * inv0};
    float m1[4] = {B.x * inv1, B.y * inv1, B.z * inv1, B.w * inv1};
    float4 sv0 = xr[(size_t)n0 * 16 + r];  // identical across q groups
    float4 sv1 = xr[(size_t)n1 * 16 + r];
    float s0[4] = {sv0.x, sv0.y, sv0.z, sv0.w};
    float s1[4] = {sv1.x, sv1.y, sv1.z, sv1.w};

    // dual-node matvec: lane (k>>2) holds dims [4(k>>2),4(k>>2)+4)
    float a0n = bj, a0s = 0.f, a1n = bj, a1s = 0.f;
#pragma unroll
    for (int k = 0; k < DIM; ++k) {
      float wnk = sWn[k * DIM + j];
      float wsk = sWs[k * DIM + j];
      a0n = fmaf(lane_bcast(m0[k & 3], k >> 2), wnk, a0n);
      a0s = fmaf(lane_bcast(s0[k & 3], k >> 2), wsk, a0s);
      a1n = fmaf(lane_bcast(m1[k & 3], k >> 2), wnk, a1n);
      a1s = fmaf(lane_bcast(s1[k & 3], k >> 2), wsk, a1s);
    }
    out[(size_t)n0 * DIM + j] = fmaxf(a0n + a0s, 0.0f);
    out[(size_t)n1 * DIM + j] = fmaxf(a1n + a1s, 0.0f);
  }
}

extern "C" void kernel_launch(void* const* d_in, const int* in_sizes, int n_in,
                              void* d_out, int out_size, void* d_ws, size_t ws_size,
                              hipStream_t stream) {
  const float* x   = (const float*)d_in[0];
  const int*   ei  = (const int*)d_in[1];
  const float* Wn1 = (const float*)d_in[2];
  const float* Ws1 = (const float*)d_in[3];
  const float* b1  = (const float*)d_in[4];
  const float* Wn2 = (const float*)d_in[5];
  const float* Ws2 = (const float*)d_in[6];
  const float* b2  = (const float*)d_in[7];
  const int* src = ei;
  const int* dst = ei + N_EDGES;

  // ws layout (ints): deg[N] | offs[N+1] | cursor[N] | bsums[512] | csr[E] | h1[N*64]f
  int* deg    = (int*)d_ws;
  int* offs   = deg + N_NODES;
  int* cursor = offs + N_NODES + 1;
  int* bsums  = cursor + N_NODES;
  int* csr    = bsums + 512;
  float* h1   = (float*)(csr + N_EDGES);
  float* outp = (float*)d_out;

  const int edgeBlocks = (N_EDGES + 255) / 256;
  const int fusedBlocks = 1280;  // 5 blocks/CU (LDS cap), 20 waves/CU resident

  hipMemsetAsync(deg, 0, (size_t)N_NODES * sizeof(int), stream);
  hist_deg<<<edgeBlocks, 256, 0, stream>>>(dst, deg, N_EDGES);
  block_sums<<<NB, SCAN_BLOCK, 0, stream>>>(deg, bsums, N_NODES);
  scan_bsums<<<1, 512, 0, stream>>>(bsums, NB);
  scan_final<<<NB, SCAN_BLOCK, 0, stream>>>(deg, bsums, offs, cursor, N_NODES);
  fill_csr<<<edgeBlocks, 256, 0, stream>>>(src, dst, cursor, csr, N_EDGES);

  sage_fused<<<fusedBlocks, 256, 0, stream>>>(x, offs, csr, Wn1, Ws1, b1, h1, N_NODES);
  sage_fused<<<fusedBlocks, 256, 0, stream>>>(h1, offs, csr, Wn2, Ws2, b2, outp, N_NODES);
}

// Round 9
// 473.904 us; speedup vs baseline: 2.5884x; 2.3111x over previous
//
#include <hip/hip_runtime.h>

#define N_NODES 100000
#define N_EDGES 1200000
#define DIM 64
#define SCAN_BLOCK 256
#define NB ((N_NODES + SCAN_BLOCK - 1) / SCAN_BLOCK)  // 391
#define NSHARD 8

__device__ __forceinline__ float lane_bcast(float v, int k) {
  return __int_as_float(__builtin_amdgcn_readlane(__float_as_int(v), k));
}

// butterfly-sum a float4 across the four 16-lane groups (xor 16, then 32)
__device__ __forceinline__ float4 qsum(float4 v) {
  v.x += __shfl_xor(v.x, 16); v.y += __shfl_xor(v.y, 16);
  v.z += __shfl_xor(v.z, 16); v.w += __shfl_xor(v.w, 16);
  v.x += __shfl_xor(v.x, 32); v.y += __shfl_xor(v.y, 32);
  v.z += __shfl_xor(v.z, 32); v.w += __shfl_xor(v.w, 32);
  return v;
}

// ---- CSR build (8-way sharded histograms/cursors: contention /8, and
// blockIdx&7 is the XCD round-robin heuristic -> mostly XCD-local atomics) ---

__global__ __launch_bounds__(256) void hist_deg_s(
    const int* __restrict__ dst, int* __restrict__ deg_s, int nEdges) {
  int e = blockIdx.x * blockDim.x + threadIdx.x;
  int shard = blockIdx.x & (NSHARD - 1);
  if (e < nEdges) atomicAdd(&deg_s[(size_t)shard * N_NODES + dst[e]], 1);
}

__global__ __launch_bounds__(SCAN_BLOCK) void block_sums(
    const int* __restrict__ deg_s, int* __restrict__ bsums, int n) {
  __shared__ int s[SCAN_BLOCK];
  int i = blockIdx.x * SCAN_BLOCK + threadIdx.x;
  int d = 0;
  if (i < n) {
#pragma unroll
    for (int sh = 0; sh < NSHARD; ++sh) d += deg_s[(size_t)sh * N_NODES + i];
  }
  s[threadIdx.x] = d;
  __syncthreads();
  for (int off = SCAN_BLOCK / 2; off > 0; off >>= 1) {
    if (threadIdx.x < off) s[threadIdx.x] += s[threadIdx.x + off];
    __syncthreads();
  }
  if (threadIdx.x == 0) bsums[blockIdx.x] = s[0];
}

__global__ __launch_bounds__(512) void scan_bsums(int* __restrict__ bsums, int nb) {
  __shared__ int s[512];
  int tid = threadIdx.x;
  s[tid] = (tid < nb) ? bsums[tid] : 0;
  __syncthreads();
  for (int off = 1; off < 512; off <<= 1) {
    int v = (tid >= off) ? s[tid - off] : 0;
    __syncthreads();
    s[tid] += v;
    __syncthreads();
  }
  if (tid < nb) bsums[tid] = (tid == 0) ? 0 : s[tid - 1];  // exclusive base
}

// per-block inclusive scan + block base -> offs; also per-shard cursor bases
__global__ __launch_bounds__(SCAN_BLOCK) void scan_final(
    const int* __restrict__ deg_s, const int* __restrict__ bbase,
    int* __restrict__ offs, int* __restrict__ cursor_s, int n) {
  __shared__ int s[SCAN_BLOCK];
  int i = blockIdx.x * SCAN_BLOCK + threadIdx.x;
  int ds0 = 0, ds1 = 0, ds2 = 0, ds3 = 0, ds4 = 0, ds5 = 0, ds6 = 0, ds7 = 0;
  int v = 0;
  if (i < n) {
    ds0 = deg_s[0ul * N_NODES + i]; ds1 = deg_s[1ul * N_NODES + i];
    ds2 = deg_s[2ul * N_NODES + i]; ds3 = deg_s[3ul * N_NODES + i];
    ds4 = deg_s[4ul * N_NODES + i]; ds5 = deg_s[5ul * N_NODES + i];
    ds6 = deg_s[6ul * N_NODES + i]; ds7 = deg_s[7ul * N_NODES + i];
    v = ((ds0 + ds1) + (ds2 + ds3)) + ((ds4 + ds5) + (ds6 + ds7));
  }
  s[threadIdx.x] = v;
  __syncthreads();
  for (int off = 1; off < SCAN_BLOCK; off <<= 1) {
    int t = (threadIdx.x >= off) ? s[threadIdx.x - off] : 0;
    __syncthreads();
    s[threadIdx.x] += t;
    __syncthreads();
  }
  int base = bbase[blockIdx.x];
  if (i < n) {
    int run = base + s[threadIdx.x] - v;  // exclusive
    offs[i] = run;
    cursor_s[0ul * N_NODES + i] = run; run += ds0;
    cursor_s[1ul * N_NODES + i] = run; run += ds1;
    cursor_s[2ul * N_NODES + i] = run; run += ds2;
    cursor_s[3ul * N_NODES + i] = run; run += ds3;
    cursor_s[4ul * N_NODES + i] = run; run += ds4;
    cursor_s[5ul * N_NODES + i] = run; run += ds5;
    cursor_s[6ul * N_NODES + i] = run; run += ds6;
    cursor_s[7ul * N_NODES + i] = run;
  }
  if (i == n - 1) offs[n] = base + s[threadIdx.x];
}

__global__ __launch_bounds__(256) void fill_csr_s(
    const int* __restrict__ src, const int* __restrict__ dst,
    int* __restrict__ cursor_s, int* __restrict__ csr_src, int nEdges) {
  int e = blockIdx.x * blockDim.x + threadIdx.x;
  int shard = blockIdx.x & (NSHARD - 1);
  if (e < nEdges) {
    int p = atomicAdd(&cursor_s[(size_t)shard * N_NODES + dst[e]], 1);
    csr_src[p] = src[e];
  }
}

// ---- Fused SAGE layer v6 --------------------------------------------------
// Gather: wave = (q=lane>>4, r=lane&15); one b128 gathers 4 edges x 16 B/lane;
// branch-free (clamped index + select-0 scale folds the mean divide into the
// gather fma). Cross-q reduce via shfl_xor(16,32), then a 2-instruction LDS
// transpose back to lane-j layout.
// Matvec: EXACT round-5 structure (scalar mean/self, readlane with SGPR k) —
// the only variant proven clean (VGPR 84, zero scratch). ROUND-6/7 LESSON:
// indexed private arrays in the matvec didn't unroll -> dynamic indexing ->
// scratch arrays -> ~1 GB/dispatch of spill traffic. No arrays, ever.
__global__ __launch_bounds__(256) void sage_fused(
    const float* __restrict__ xin, const int* __restrict__ offs,
    const int* __restrict__ csr_src, const float* __restrict__ Wn,
    const float* __restrict__ Ws, const float* __restrict__ bias,
    float* __restrict__ out, int nNodes) {
  __shared__ float sWn[DIM * DIM];
  __shared__ float sWs[DIM * DIM];
  __shared__ float sT[4][2][DIM];  // per-wave mean transpose buffer
  for (int i = threadIdx.x; i < DIM * DIM / 4; i += 256) {
    reinterpret_cast<float4*>(sWn)[i] = reinterpret_cast<const float4*>(Wn)[i];
    reinterpret_cast<float4*>(sWs)[i] = reinterpret_cast<const float4*>(Ws)[i];
  }
  __syncthreads();

  const float4* xr = reinterpret_cast<const float4*>(xin);
  int lane = threadIdx.x & 63;
  int q = lane >> 4;   // edge subgroup 0..3
  int r = lane & 15;   // float4 column 0..15
  int j = lane;        // output dim
  int w = threadIdx.x >> 6;
  float bj = bias[j];
  int gw = blockIdx.x * 4 + w;
  int nw = gridDim.x * 4;

  for (int p = gw; 2 * p < nNodes; p += nw) {
    int n0 = 2 * p, n1 = 2 * p + 1;
    int e0a = offs[n0], e1a = offs[n0 + 1];
    int e0b = offs[n1], e1b = offs[n1 + 1];
    float inv0 = 1.0f / fmaxf((float)(e1a - e0a), 1.0f);
    float inv1 = 1.0f / fmaxf((float)(e1b - e0b), 1.0f);
    float self0 = xin[(size_t)n0 * DIM + j];
    float self1 = xin[(size_t)n1 * DIM + j];

    // branch-free dual-node float4 gather, mean scale folded in
    float4 A = {0, 0, 0, 0}, B = {0, 0, 0, 0};
    int ea = e0a + q, eb = e0b + q;
    int rem = max(e1a - e0a, e1b - e0b);
    for (; rem > 0; rem -= 4, ea += 4, eb += 4) {
      int ca = max(min(ea, e1a - 1), 0);   // always a valid csr index
      int cb = max(min(eb, e1b - 1), 0);
      int sa = csr_src[ca];
      int sb = csr_src[cb];
      float fa = (ea < e1a) ? inv0 : 0.0f;
      float fb = (eb < e1b) ? inv1 : 0.0f;
      float4 va = xr[(size_t)sa * 16 + r];
      float4 vb = xr[(size_t)sb * 16 + r];
      A.x = fmaf(va.x, fa, A.x); A.y = fmaf(va.y, fa, A.y);
      A.z = fmaf(va.z, fa, A.z); A.w = fmaf(va.w, fa, A.w);
      B.x = fmaf(vb.x, fb, B.x); B.y = fmaf(vb.y, fb, B.y);
      B.z = fmaf(vb.z, fb, B.z); B.w = fmaf(vb.w, fb, B.w);
    }
    A = qsum(A);  // lanes with equal r now hold mean dims [4r,4r+4) of n0
    B = qsum(B);
    if (lane < 16) {  // q==0 writes the transpose
      reinterpret_cast<float4*>(sT[w][0])[r] = A;
      reinterpret_cast<float4*>(sT[w][1])[r] = B;
    }
    float mean0 = sT[w][0][j];  // same-wave LDS; compiler inserts lgkmcnt wait
    float mean1 = sT[w][1][j];

    // round-5 matvec: 4 independent chains, readlane with SGPR loop index
    float a0n = bj, a0s = 0.f, a1n = bj, a1s = 0.f;
#pragma unroll
    for (int k = 0; k < DIM; ++k) {
      float wnk = sWn[k * DIM + j];
      float wsk = sWs[k * DIM + j];
      a0n = fmaf(lane_bcast(mean0, k), wnk, a0n);
      a0s = fmaf(lane_bcast(self0, k), wsk, a0s);
      a1n = fmaf(lane_bcast(mean1, k), wnk, a1n);
      a1s = fmaf(lane_bcast(self1, k), wsk, a1s);
    }
    out[(size_t)n0 * DIM + j] = fmaxf(a0n + a0s, 0.0f);
    out[(size_t)n1 * DIM + j] = fmaxf(a1n + a1s, 0.0f);
  }
}

extern "C" void kernel_launch(void* const* d_in, const int* in_sizes, int n_in,
                              void* d_out, int out_size, void* d_ws, size_t ws_size,
                              hipStream_t stream) {
  const float* x   = (const float*)d_in[0];
  const int*   ei  = (const int*)d_in[1];
  const float* Wn1 = (const float*)d_in[2];
  const float* Ws1 = (const float*)d_in[3];
  const float* b1  = (const float*)d_in[4];
  const float* Wn2 = (const float*)d_in[5];
  const float* Ws2 = (const float*)d_in[6];
  const float* b2  = (const float*)d_in[7];
  const int* src = ei;
  const int* dst = ei + N_EDGES;

  // ws (ints): deg_s[8N] | offs[N+1] | cursor_s[8N] | bsums[512] | csr[E] | h1[N*64]f
  int* deg_s    = (int*)d_ws;
  int* offs     = deg_s + (size_t)NSHARD * N_NODES;
  int* cursor_s = offs + N_NODES + 1;
  int* bsums    = cursor_s + (size_t)NSHARD * N_NODES;
  int* csr      = bsums + 512;
  float* h1     = (float*)(csr + N_EDGES);
  float* outp   = (float*)d_out;

  const int edgeBlocks = (N_EDGES + 255) / 256;
  const int fusedBlocks = 1024;  // 4 blocks/CU (34 KB LDS each), 16 waves/CU

  hipMemsetAsync(deg_s, 0, (size_t)NSHARD * N_NODES * sizeof(int), stream);
  hist_deg_s<<<edgeBlocks, 256, 0, stream>>>(dst, deg_s, N_EDGES);
  block_sums<<<NB, SCAN_BLOCK, 0, stream>>>(deg_s, bsums, N_NODES);
  scan_bsums<<<1, 512, 0, stream>>>(bsums, NB);
  scan_final<<<NB, SCAN_BLOCK, 0, stream>>>(deg_s, bsums, offs, cursor_s, N_NODES);
  fill_csr_s<<<edgeBlocks, 256, 0, stream>>>(src, dst, cursor_s, csr, N_EDGES);

  sage_fused<<<fusedBlocks, 256, 0, stream>>>(x, offs, csr, Wn1, Ws1, b1, h1, N_NODES);
  sage_fused<<<fusedBlocks, 256, 0, stream>>>(h1, offs, csr, Wn2, Ws2, b2, outp, N_NODES);
}